// Round 4
// baseline (452.241 us; speedup 1.0000x reference)
//
#include <hip/hip_runtime.h>
#include <hip/hip_bf16.h>
#include <cstdint>

#define AXIS_CAP 32
#define GRID_SIZE_F 0.04f
#define BINS_PER_BATCH (AXIS_CAP * AXIS_CAP * AXIS_CAP)   // 32768
#define SCAN_TPB 256
#define BINS_PER_THREAD 4
#define BINS_PER_BLOCK (SCAN_TPB * BINS_PER_THREAD)       // 1024

typedef float f32x4 __attribute__((ext_vector_type(4)));  // nontemporal-legal

__device__ __forceinline__ int point_batch(int i, const int* offs, int B) {
    int b = 0;
    for (int k = 0; k < B; ++k) b += (offs[k] <= i);
    return b;
}

// ---- init scratch ----
__global__ void init_kernel(uint32_t* binCount, float* binSumX, float* binSumY,
                            float* binSumZ, int nbins, int* startBits, int B) {
    int i = blockIdx.x * blockDim.x + threadIdx.x;
    int stride = gridDim.x * blockDim.x;
    for (int v = i; v < nbins; v += stride) {
        binCount[v] = 0;
        binSumX[v] = 0.f; binSumY[v] = 0.f; binSumZ[v] = 0.f;
    }
    if (i < 3 * B) startBits[i] = 0x7F800000;  // +inf
}

// ---- per-batch min coord, hierarchical: reg -> wave shuffle -> LDS -> global ----
__global__ __launch_bounds__(256) void batch_min4_kernel(
        const float* __restrict__ coord, const int* __restrict__ offs,
        int B, int N, int* __restrict__ startBits) {
    __shared__ int smin[12];
    if (threadIdx.x < 12) smin[threadIdx.x] = 0x7F800000;
    __syncthreads();

    int o0 = offs[0];
    int o1 = (B > 1) ? offs[1] : o0;
    int o2 = (B > 2) ? offs[2] : o1;

    float m[4][3];
#pragma unroll
    for (int bb = 0; bb < 4; ++bb)
#pragma unroll
        for (int d = 0; d < 3; ++d) m[bb][d] = INFINITY;

    int gid = blockIdx.x * blockDim.x + threadIdx.x;
    int stride = gridDim.x * blockDim.x;
    for (int i = gid; i < N; i += stride) {
        float x = coord[(size_t)i * 3 + 0];
        float y = coord[(size_t)i * 3 + 1];
        float z = coord[(size_t)i * 3 + 2];
        int b = (i >= o0) + (i >= o1) + (i >= o2);
#pragma unroll
        for (int bb = 0; bb < 4; ++bb) {
            bool sel = (bb == b);
            m[bb][0] = fminf(m[bb][0], sel ? x : INFINITY);
            m[bb][1] = fminf(m[bb][1], sel ? y : INFINITY);
            m[bb][2] = fminf(m[bb][2], sel ? z : INFINITY);
        }
    }

#pragma unroll
    for (int bb = 0; bb < 4; ++bb)
#pragma unroll
        for (int d = 0; d < 3; ++d) {
            float v = m[bb][d];
            for (int off = 32; off > 0; off >>= 1)
                v = fminf(v, __shfl_xor(v, off));
            m[bb][d] = v;
        }

    if ((threadIdx.x & 63) == 0) {
#pragma unroll
        for (int bb = 0; bb < 4; ++bb)
#pragma unroll
            for (int d = 0; d < 3; ++d)
                atomicMin(&smin[bb * 3 + d], __float_as_int(m[bb][d]));
    }
    __syncthreads();
    if (threadIdx.x < 12 && (threadIdx.x / 3) < B)
        atomicMin(&startBits[threadIdx.x], smin[threadIdx.x]);
}

// ---- generic fallback for B > 4 ----
__global__ void batch_min_generic_kernel(const float* __restrict__ coord,
                                         const int* __restrict__ offs,
                                         int B, int N, int* startBits) {
    int i = blockIdx.x * blockDim.x + threadIdx.x;
    if (i >= N) return;
    int b = point_batch(i, offs, B);
    for (int d = 0; d < 3; ++d) {
        float c = coord[(size_t)i * 3 + d];
        atomicMin(&startBits[b * 3 + d], __float_as_int(c));
    }
}

// ---- per-point voxel key + histogram + coord sum accumulation ----
__global__ void keys_count_kernel(const float* __restrict__ coord,
                                  const int* __restrict__ offs,
                                  const int* __restrict__ startBits,
                                  int B, int N,
                                  uint32_t* __restrict__ keys,
                                  uint32_t* __restrict__ binCount,
                                  float* __restrict__ binSumX,
                                  float* __restrict__ binSumY,
                                  float* __restrict__ binSumZ) {
    int i = blockIdx.x * blockDim.x + threadIdx.x;
    if (i >= N) return;
    int b = point_batch(i, offs, B);
    float c3[3];
    int v[3];
    for (int d = 0; d < 3; ++d) {
        float s = __int_as_float(startBits[b * 3 + d]);
        float c = coord[(size_t)i * 3 + d];
        c3[d] = c;
        float q = (c - s) / GRID_SIZE_F;            // IEEE div, matches ref
        int vi = (int)floorf(q);
        vi = vi < 0 ? 0 : (vi > AXIS_CAP - 1 ? AXIS_CAP - 1 : vi);
        v[d] = vi;
    }
    uint32_t key = ((uint32_t)b * AXIS_CAP + v[0]) * AXIS_CAP * AXIS_CAP
                 + (uint32_t)v[1] * AXIS_CAP + v[2];
    keys[i] = key;
    atomicAdd(&binCount[key], 1u);
    atomicAdd(&binSumX[key], c3[0]);
    atomicAdd(&binSumY[key], c3[1]);
    atomicAdd(&binSumZ[key], c3[2]);
}

// ---- scan pass 1 ----
__global__ void scan1_kernel(const uint32_t* __restrict__ binCount,
                             uint32_t* __restrict__ binStart,
                             uint32_t* __restrict__ binSeg,
                             uint32_t* __restrict__ blockCnt,
                             uint32_t* __restrict__ blockOcc) {
    __shared__ uint32_t sC[SCAN_TPB], sO[SCAN_TPB];
    int t = threadIdx.x;
    int base = blockIdx.x * BINS_PER_BLOCK + t * BINS_PER_THREAD;
    uint32_t c[BINS_PER_THREAD];
    uint32_t tc = 0, to = 0;
#pragma unroll
    for (int j = 0; j < BINS_PER_THREAD; ++j) {
        c[j] = binCount[base + j];
        tc += c[j];
        to += (c[j] > 0u);
    }
    sC[t] = tc; sO[t] = to;
    __syncthreads();
    for (int off = 1; off < SCAN_TPB; off <<= 1) {
        uint32_t a = 0, b2 = 0;
        if (t >= off) { a = sC[t - off]; b2 = sO[t - off]; }
        __syncthreads();
        sC[t] += a; sO[t] += b2;
        __syncthreads();
    }
    uint32_t exC = sC[t] - tc;
    uint32_t exO = sO[t] - to;
#pragma unroll
    for (int j = 0; j < BINS_PER_THREAD; ++j) {
        binStart[base + j] = exC;
        binSeg[base + j] = exO;
        exC += c[j];
        exO += (c[j] > 0u);
    }
    if (t == SCAN_TPB - 1) {
        blockCnt[blockIdx.x] = sC[t];
        blockOcc[blockIdx.x] = sO[t];
    }
}

// ---- scan pass 2 ----
__global__ void scan2_kernel(uint32_t* blockCnt, uint32_t* blockOcc,
                             uint32_t* totals, int nb) {
    __shared__ uint32_t sC[SCAN_TPB], sO[SCAN_TPB];
    int t = threadIdx.x;
    uint32_t c = (t < nb) ? blockCnt[t] : 0u;
    uint32_t o = (t < nb) ? blockOcc[t] : 0u;
    sC[t] = c; sO[t] = o;
    __syncthreads();
    for (int off = 1; off < SCAN_TPB; off <<= 1) {
        uint32_t a = 0, b2 = 0;
        if (t >= off) { a = sC[t - off]; b2 = sO[t - off]; }
        __syncthreads();
        sC[t] += a; sO[t] += b2;
        __syncthreads();
    }
    if (t < nb) { blockCnt[t] = sC[t] - c; blockOcc[t] = sO[t] - o; }
    if (t == SCAN_TPB - 1) { totals[0] = sO[t]; totals[1] = sC[t]; }
}

// ---- scan pass 3: add block offsets; also emit cursor = final binStart ----
__global__ void scan3_kernel(uint32_t* __restrict__ binStart,
                             uint32_t* __restrict__ binSeg,
                             uint32_t* __restrict__ cursor,
                             const uint32_t* __restrict__ blockCnt,
                             const uint32_t* __restrict__ blockOcc) {
    int t = threadIdx.x;
    int base = blockIdx.x * BINS_PER_BLOCK + t * BINS_PER_THREAD;
    uint32_t oc = blockCnt[blockIdx.x];
    uint32_t oo = blockOcc[blockIdx.x];
#pragma unroll
    for (int j = 0; j < BINS_PER_THREAD; ++j) {
        uint32_t s = binStart[base + j] + oc;
        binStart[base + j] = s;
        cursor[base + j] = s;
        binSeg[base + j] += oo;
    }
}

// ---- scatter: cursor doubles as the running insert position ----
__global__ void scatter_kernel(const uint32_t* __restrict__ keys,
                               uint32_t* __restrict__ cursor,
                               uint32_t* __restrict__ pointIdx, int N) {
    int i = blockIdx.x * blockDim.x + threadIdx.x;
    if (i >= N) return;
    uint32_t pos = atomicAdd(&cursor[keys[i]], 1u);
    pointIdx[pos] = (uint32_t)i;
}

// ---- per-voxel reduction: one 64-thread wave per bin ----
// 4 row-groups x 16 lanes; each lane loads a float4 (4 channels) -> one wave
// issue covers 4 rows (1 KiB), pointIdx loaded 64-at-a-time and shfl-broadcast.
__global__ __launch_bounds__(64) void reduce_kernel(
        const float* __restrict__ feat,
        const uint32_t* __restrict__ binCount,
        const uint32_t* __restrict__ binStart,
        const uint32_t* __restrict__ binSeg,
        const float* __restrict__ binSumX,
        const float* __restrict__ binSumY,
        const float* __restrict__ binSumZ,
        const uint32_t* __restrict__ pointIdx,
        float* __restrict__ out, int N, int C) {
    int bin = blockIdx.x;
    uint32_t cnt = binCount[bin];
    if (cnt == 0u) return;
    uint32_t st = binStart[bin];
    uint32_t seg = binSeg[bin];
    int lane = threadIdx.x;
    float* feat_out = out + (size_t)N * 3;

    if ((C & 3) == 0 && C <= 64) {
        int g = lane >> 4;          // row group 0..3
        int l4 = lane & 15;         // float4 slot within row
        int q4 = C >> 2;            // float4s per row (16 for C=64)
        f32x4 mx = {-INFINITY, -INFINITY, -INFINITY, -INFINITY};
        for (uint32_t base = 0; base < cnt; base += 64) {
            uint32_t nchunk = min(64u, cnt - base);
            uint32_t myIdx = (lane < (int)nchunk) ? pointIdx[st + base + lane] : 0u;
            for (uint32_t p = (uint32_t)g; p < nchunk; p += 4) {
                uint32_t idx = __shfl(myIdx, (int)p);
                if (l4 < q4) {
                    const f32x4* row = (const f32x4*)(feat + (size_t)idx * C);
                    f32x4 v = row[l4];
                    mx.x = fmaxf(mx.x, v.x);
                    mx.y = fmaxf(mx.y, v.y);
                    mx.z = fmaxf(mx.z, v.z);
                    mx.w = fmaxf(mx.w, v.w);
                }
            }
        }
        // merge the 4 row groups (lanes l4, l4+16, l4+32, l4+48)
        mx.x = fmaxf(mx.x, __shfl_xor(mx.x, 16));
        mx.y = fmaxf(mx.y, __shfl_xor(mx.y, 16));
        mx.z = fmaxf(mx.z, __shfl_xor(mx.z, 16));
        mx.w = fmaxf(mx.w, __shfl_xor(mx.w, 16));
        mx.x = fmaxf(mx.x, __shfl_xor(mx.x, 32));
        mx.y = fmaxf(mx.y, __shfl_xor(mx.y, 32));
        mx.z = fmaxf(mx.z, __shfl_xor(mx.z, 32));
        mx.w = fmaxf(mx.w, __shfl_xor(mx.w, 32));
        if (g == 0 && l4 < q4)
            ((f32x4*)(feat_out + (size_t)seg * C))[l4] = mx;
    } else {
        for (int c = lane; c < C; c += 64) {
            float m = -INFINITY;
            for (uint32_t p = 0; p < cnt; ++p) {
                uint32_t idx = pointIdx[st + p];
                m = fmaxf(m, feat[(size_t)idx * C + c]);
            }
            feat_out[(size_t)seg * C + c] = m;
        }
    }

    if (lane < 3) {
        float s = (lane == 0) ? binSumX[bin] : (lane == 1) ? binSumY[bin]
                                                           : binSumZ[bin];
        out[(size_t)seg * 3 + lane] = s / (float)cnt;
    }
}

// ---- zero padding rows >= n_vox ----
__global__ void pad_kernel(float* __restrict__ out,
                           const uint32_t* __restrict__ totals, int N, int C) {
    uint32_t nvox = totals[0];
    size_t gid = (size_t)blockIdx.x * blockDim.x + threadIdx.x;
    size_t stride = (size_t)gridDim.x * blockDim.x;
    float* featBase = out + (size_t)N * 3;
    f32x4 z4 = {0.f, 0.f, 0.f, 0.f};
    if ((C & 3) == 0) {
        f32x4* f4 = (f32x4*)featBase;
        size_t r4 = (size_t)C / 4;
        size_t v0 = (size_t)nvox * r4, v1 = (size_t)N * r4;
        for (size_t v = v0 + gid; v < v1; v += stride)
            __builtin_nontemporal_store(z4, &f4[v]);
    } else {
        size_t e0 = (size_t)nvox * C, e1 = (size_t)N * C;
        for (size_t e = e0 + gid; e < e1; e += stride)
            __builtin_nontemporal_store(0.f, &featBase[e]);
    }
    size_t c0 = (size_t)nvox * 3, c1 = (size_t)N * 3;
    for (size_t e = c0 + gid; e < c1; e += stride)
        __builtin_nontemporal_store(0.f, &out[e]);
}

// ---- offset_out + n_vox ----
__global__ void finalize_kernel(const uint32_t* __restrict__ binSeg,
                                const uint32_t* __restrict__ totals,
                                float* __restrict__ out, int B, int N, int C) {
    int t = threadIdx.x;
    uint32_t nvox = totals[0];
    float* tail = out + (size_t)N * 3 + (size_t)N * C;
    if (t < B) {
        uint32_t v = (t == B - 1) ? nvox
                                  : binSeg[(size_t)(t + 1) * BINS_PER_BATCH];
        tail[t] = (float)v;
    }
    if (t == 0) tail[B] = (float)nvox;
}

extern "C" void kernel_launch(void* const* d_in, const int* in_sizes, int n_in,
                              void* d_out, int out_size, void* d_ws, size_t ws_size,
                              hipStream_t stream) {
    const float* coord = (const float*)d_in[0];
    const float* feat  = (const float*)d_in[1];
    const int*   offs  = (const int*)d_in[2];
    float* out = (float*)d_out;

    int N = in_sizes[0] / 3;
    int C = in_sizes[1] / N;
    int B = in_sizes[2];
    int NBINS = B * BINS_PER_BATCH;          // 131072 for B=4
    int NB1 = NBINS / BINS_PER_BLOCK;        // 128

    // workspace layout
    uint8_t* w = (uint8_t*)d_ws;
    uint32_t* binCount = (uint32_t*)w;              w += (size_t)NBINS * 4;
    uint32_t* binStart = (uint32_t*)w;              w += (size_t)NBINS * 4;
    uint32_t* binSeg   = (uint32_t*)w;              w += (size_t)NBINS * 4;
    uint32_t* cursor   = (uint32_t*)w;              w += (size_t)NBINS * 4;
    float*    binSumX  = (float*)w;                 w += (size_t)NBINS * 4;
    float*    binSumY  = (float*)w;                 w += (size_t)NBINS * 4;
    float*    binSumZ  = (float*)w;                 w += (size_t)NBINS * 4;
    uint32_t* blockCnt = (uint32_t*)w;              w += (size_t)NB1 * 4;
    uint32_t* blockOcc = (uint32_t*)w;              w += (size_t)NB1 * 4;
    uint32_t* totals   = (uint32_t*)w;              w += 2 * 4;
    int*      startBits= (int*)w;                   w += (size_t)3 * B * 4 + 8;
    uint32_t* keys     = (uint32_t*)w;              w += (size_t)N * 4;
    uint32_t* pointIdx = (uint32_t*)w;              /* w += N*4 */

    int ptBlocks = (N + 255) / 256;

    init_kernel<<<512, 256, 0, stream>>>(binCount, binSumX, binSumY, binSumZ,
                                         NBINS, startBits, B);
    if (B <= 4) {
        batch_min4_kernel<<<1024, 256, 0, stream>>>(coord, offs, B, N, startBits);
    } else {
        batch_min_generic_kernel<<<ptBlocks, 256, 0, stream>>>(coord, offs, B, N,
                                                               startBits);
    }
    keys_count_kernel<<<ptBlocks, 256, 0, stream>>>(coord, offs, startBits, B, N,
                                                    keys, binCount,
                                                    binSumX, binSumY, binSumZ);
    scan1_kernel<<<NB1, SCAN_TPB, 0, stream>>>(binCount, binStart, binSeg,
                                               blockCnt, blockOcc);
    scan2_kernel<<<1, SCAN_TPB, 0, stream>>>(blockCnt, blockOcc, totals, NB1);
    scan3_kernel<<<NB1, SCAN_TPB, 0, stream>>>(binStart, binSeg, cursor,
                                               blockCnt, blockOcc);
    scatter_kernel<<<ptBlocks, 256, 0, stream>>>(keys, cursor, pointIdx, N);
    reduce_kernel<<<NBINS, 64, 0, stream>>>(feat, binCount, binStart, binSeg,
                                            binSumX, binSumY, binSumZ,
                                            pointIdx, out, N, C);
    pad_kernel<<<2048, 256, 0, stream>>>(out, totals, N, C);
    finalize_kernel<<<1, 64, 0, stream>>>(binSeg, totals, out, B, N, C);
}

// Round 5
// 230.633 us; speedup vs baseline: 1.9609x; 1.9609x over previous
//
#include <hip/hip_runtime.h>
#include <hip/hip_bf16.h>
#include <cstdint>

#define AXIS_CAP 32
#define GRID_SIZE_F 0.04f
#define BINS_PER_BATCH (AXIS_CAP * AXIS_CAP * AXIS_CAP)   // 32768
#define SCAN_TPB 256
#define BINS_PER_THREAD 4
#define BINS_PER_BLOCK (SCAN_TPB * BINS_PER_THREAD)       // 1024

typedef float f32x4 __attribute__((ext_vector_type(4)));  // nontemporal-legal

__device__ __forceinline__ int point_batch(int i, const int* offs, int B) {
    int b = 0;
    for (int k = 0; k < B; ++k) b += (offs[k] <= i);
    return b;
}

// ---- init scratch ----
__global__ void init_kernel(uint32_t* binCount, int nbins, int* startBits, int B) {
    int i = blockIdx.x * blockDim.x + threadIdx.x;
    int stride = gridDim.x * blockDim.x;
    for (int v = i; v < nbins; v += stride) binCount[v] = 0;
    if (i < 3 * B) startBits[i] = 0x7F800000;  // +inf
}

// ---- per-batch min coord, hierarchical: reg -> wave shuffle -> LDS -> global ----
__global__ __launch_bounds__(256) void batch_min4_kernel(
        const float* __restrict__ coord, const int* __restrict__ offs,
        int B, int N, int* __restrict__ startBits) {
    __shared__ int smin[12];
    if (threadIdx.x < 12) smin[threadIdx.x] = 0x7F800000;
    __syncthreads();

    int o0 = offs[0];
    int o1 = (B > 1) ? offs[1] : o0;
    int o2 = (B > 2) ? offs[2] : o1;

    float m[4][3];
#pragma unroll
    for (int bb = 0; bb < 4; ++bb)
#pragma unroll
        for (int d = 0; d < 3; ++d) m[bb][d] = INFINITY;

    int gid = blockIdx.x * blockDim.x + threadIdx.x;
    int stride = gridDim.x * blockDim.x;
    for (int i = gid; i < N; i += stride) {
        float x = coord[(size_t)i * 3 + 0];
        float y = coord[(size_t)i * 3 + 1];
        float z = coord[(size_t)i * 3 + 2];
        int b = (i >= o0) + (i >= o1) + (i >= o2);
#pragma unroll
        for (int bb = 0; bb < 4; ++bb) {
            bool sel = (bb == b);
            m[bb][0] = fminf(m[bb][0], sel ? x : INFINITY);
            m[bb][1] = fminf(m[bb][1], sel ? y : INFINITY);
            m[bb][2] = fminf(m[bb][2], sel ? z : INFINITY);
        }
    }

#pragma unroll
    for (int bb = 0; bb < 4; ++bb)
#pragma unroll
        for (int d = 0; d < 3; ++d) {
            float v = m[bb][d];
            for (int off = 32; off > 0; off >>= 1)
                v = fminf(v, __shfl_xor(v, off));
            m[bb][d] = v;
        }

    if ((threadIdx.x & 63) == 0) {
#pragma unroll
        for (int bb = 0; bb < 4; ++bb)
#pragma unroll
            for (int d = 0; d < 3; ++d)
                atomicMin(&smin[bb * 3 + d], __float_as_int(m[bb][d]));
    }
    __syncthreads();
    if (threadIdx.x < 12 && (threadIdx.x / 3) < B)
        atomicMin(&startBits[threadIdx.x], smin[threadIdx.x]);
}

// ---- generic fallback for B > 4 ----
__global__ void batch_min_generic_kernel(const float* __restrict__ coord,
                                         const int* __restrict__ offs,
                                         int B, int N, int* startBits) {
    int i = blockIdx.x * blockDim.x + threadIdx.x;
    if (i >= N) return;
    int b = point_batch(i, offs, B);
    for (int d = 0; d < 3; ++d) {
        float c = coord[(size_t)i * 3 + d];
        atomicMin(&startBits[b * 3 + d], __float_as_int(c));
    }
}

// ---- per-point voxel key + histogram; the atomicAdd's return value IS the
// in-bin rank, which makes the later scatter atomic-free ----
__global__ void keys_count_kernel(const float* __restrict__ coord,
                                  const int* __restrict__ offs,
                                  const int* __restrict__ startBits,
                                  int B, int N,
                                  uint32_t* __restrict__ keys,
                                  uint32_t* __restrict__ rank,
                                  uint32_t* __restrict__ binCount) {
    int i = blockIdx.x * blockDim.x + threadIdx.x;
    if (i >= N) return;
    int b = point_batch(i, offs, B);
    int v[3];
    for (int d = 0; d < 3; ++d) {
        float s = __int_as_float(startBits[b * 3 + d]);
        float q = (coord[(size_t)i * 3 + d] - s) / GRID_SIZE_F;  // IEEE div
        int vi = (int)floorf(q);
        vi = vi < 0 ? 0 : (vi > AXIS_CAP - 1 ? AXIS_CAP - 1 : vi);
        v[d] = vi;
    }
    uint32_t key = ((uint32_t)b * AXIS_CAP + v[0]) * AXIS_CAP * AXIS_CAP
                 + (uint32_t)v[1] * AXIS_CAP + v[2];
    keys[i] = key;
    rank[i] = atomicAdd(&binCount[key], 1u);
}

// ---- scan pass 1 ----
__global__ void scan1_kernel(const uint32_t* __restrict__ binCount,
                             uint32_t* __restrict__ binStart,
                             uint32_t* __restrict__ binSeg,
                             uint32_t* __restrict__ blockCnt,
                             uint32_t* __restrict__ blockOcc) {
    __shared__ uint32_t sC[SCAN_TPB], sO[SCAN_TPB];
    int t = threadIdx.x;
    int base = blockIdx.x * BINS_PER_BLOCK + t * BINS_PER_THREAD;
    uint32_t c[BINS_PER_THREAD];
    uint32_t tc = 0, to = 0;
#pragma unroll
    for (int j = 0; j < BINS_PER_THREAD; ++j) {
        c[j] = binCount[base + j];
        tc += c[j];
        to += (c[j] > 0u);
    }
    sC[t] = tc; sO[t] = to;
    __syncthreads();
    for (int off = 1; off < SCAN_TPB; off <<= 1) {
        uint32_t a = 0, b2 = 0;
        if (t >= off) { a = sC[t - off]; b2 = sO[t - off]; }
        __syncthreads();
        sC[t] += a; sO[t] += b2;
        __syncthreads();
    }
    uint32_t exC = sC[t] - tc;
    uint32_t exO = sO[t] - to;
#pragma unroll
    for (int j = 0; j < BINS_PER_THREAD; ++j) {
        binStart[base + j] = exC;
        binSeg[base + j] = exO;
        exC += c[j];
        exO += (c[j] > 0u);
    }
    if (t == SCAN_TPB - 1) {
        blockCnt[blockIdx.x] = sC[t];
        blockOcc[blockIdx.x] = sO[t];
    }
}

// ---- scan pass 2 ----
__global__ void scan2_kernel(uint32_t* blockCnt, uint32_t* blockOcc,
                             uint32_t* totals, int nb) {
    __shared__ uint32_t sC[SCAN_TPB], sO[SCAN_TPB];
    int t = threadIdx.x;
    uint32_t c = (t < nb) ? blockCnt[t] : 0u;
    uint32_t o = (t < nb) ? blockOcc[t] : 0u;
    sC[t] = c; sO[t] = o;
    __syncthreads();
    for (int off = 1; off < SCAN_TPB; off <<= 1) {
        uint32_t a = 0, b2 = 0;
        if (t >= off) { a = sC[t - off]; b2 = sO[t - off]; }
        __syncthreads();
        sC[t] += a; sO[t] += b2;
        __syncthreads();
    }
    if (t < nb) { blockCnt[t] = sC[t] - c; blockOcc[t] = sO[t] - o; }
    if (t == SCAN_TPB - 1) { totals[0] = sO[t]; totals[1] = sC[t]; }
}

// ---- scan pass 3: add block offsets ----
__global__ void scan3_kernel(uint32_t* __restrict__ binStart,
                             uint32_t* __restrict__ binSeg,
                             const uint32_t* __restrict__ blockCnt,
                             const uint32_t* __restrict__ blockOcc) {
    int t = threadIdx.x;
    int base = blockIdx.x * BINS_PER_BLOCK + t * BINS_PER_THREAD;
    uint32_t oc = blockCnt[blockIdx.x];
    uint32_t oo = blockOcc[blockIdx.x];
#pragma unroll
    for (int j = 0; j < BINS_PER_THREAD; ++j) {
        binStart[base + j] += oc;
        binSeg[base + j] += oo;
    }
}

// ---- scatter: atomic-free (pos = binStart[key] + rank) ----
__global__ void scatter_kernel(const uint32_t* __restrict__ keys,
                               const uint32_t* __restrict__ rank,
                               const uint32_t* __restrict__ binStart,
                               uint32_t* __restrict__ pointIdx, int N) {
    int i = blockIdx.x * blockDim.x + threadIdx.x;
    if (i >= N) return;
    uint32_t pos = binStart[keys[i]] + rank[i];
    pointIdx[pos] = (uint32_t)i;
}

// ---- per-voxel reduction: one 64-thread wave per bin ----
// feat max: 4 row-groups x 16 lanes, float4 per lane -> 4 rows (1 KiB) per
// wave issue; pointIdx loaded 64-wide and shfl-broadcast. coord mean:
// accumulated from the same 64-wide chunk, butterfly-reduced.
__global__ __launch_bounds__(64) void reduce_kernel(
        const float* __restrict__ coord, const float* __restrict__ feat,
        const uint32_t* __restrict__ binCount,
        const uint32_t* __restrict__ binStart,
        const uint32_t* __restrict__ binSeg,
        const uint32_t* __restrict__ pointIdx,
        float* __restrict__ out, int N, int C) {
    int bin = blockIdx.x;
    uint32_t cnt = binCount[bin];
    if (cnt == 0u) return;
    uint32_t st = binStart[bin];
    uint32_t seg = binSeg[bin];
    int lane = threadIdx.x;
    float* feat_out = out + (size_t)N * 3;

    float sx = 0.f, sy = 0.f, sz = 0.f;

    if ((C & 3) == 0 && C <= 64) {
        int g = lane >> 4;          // row group 0..3
        int l4 = lane & 15;         // float4 slot within row
        int q4 = C >> 2;            // float4s per row (16 for C=64)
        f32x4 mx = {-INFINITY, -INFINITY, -INFINITY, -INFINITY};
        for (uint32_t base = 0; base < cnt; base += 64) {
            uint32_t nchunk = min(64u, cnt - base);
            bool valid = lane < (int)nchunk;
            uint32_t myIdx = valid ? pointIdx[st + base + lane] : 0u;
            if (valid) {
                sx += coord[(size_t)myIdx * 3 + 0];
                sy += coord[(size_t)myIdx * 3 + 1];
                sz += coord[(size_t)myIdx * 3 + 2];
            }
            for (uint32_t p = (uint32_t)g; p < nchunk; p += 4) {
                uint32_t idx = __shfl(myIdx, (int)p);
                if (l4 < q4) {
                    const f32x4* row = (const f32x4*)(feat + (size_t)idx * C);
                    f32x4 v = row[l4];
                    mx.x = fmaxf(mx.x, v.x);
                    mx.y = fmaxf(mx.y, v.y);
                    mx.z = fmaxf(mx.z, v.z);
                    mx.w = fmaxf(mx.w, v.w);
                }
            }
        }
        // merge the 4 row groups (lanes l4, l4+16, l4+32, l4+48)
        mx.x = fmaxf(mx.x, __shfl_xor(mx.x, 16));
        mx.y = fmaxf(mx.y, __shfl_xor(mx.y, 16));
        mx.z = fmaxf(mx.z, __shfl_xor(mx.z, 16));
        mx.w = fmaxf(mx.w, __shfl_xor(mx.w, 16));
        mx.x = fmaxf(mx.x, __shfl_xor(mx.x, 32));
        mx.y = fmaxf(mx.y, __shfl_xor(mx.y, 32));
        mx.z = fmaxf(mx.z, __shfl_xor(mx.z, 32));
        mx.w = fmaxf(mx.w, __shfl_xor(mx.w, 32));
        if (g == 0 && l4 < q4)
            ((f32x4*)(feat_out + (size_t)seg * C))[l4] = mx;
    } else {
        for (uint32_t p = lane; p < cnt; p += 64) {
            uint32_t idx = pointIdx[st + p];
            sx += coord[(size_t)idx * 3 + 0];
            sy += coord[(size_t)idx * 3 + 1];
            sz += coord[(size_t)idx * 3 + 2];
        }
        for (int c = lane; c < C; c += 64) {
            float m = -INFINITY;
            for (uint32_t p = 0; p < cnt; ++p) {
                uint32_t idx = pointIdx[st + p];
                m = fmaxf(m, feat[(size_t)idx * C + c]);
            }
            feat_out[(size_t)seg * C + c] = m;
        }
    }

    // coord mean: butterfly reduce the per-lane partials
    for (int off = 32; off > 0; off >>= 1) {
        sx += __shfl_xor(sx, off);
        sy += __shfl_xor(sy, off);
        sz += __shfl_xor(sz, off);
    }
    if (lane == 0) {
        float inv = 1.0f / (float)cnt;
        out[(size_t)seg * 3 + 0] = sx * inv;
        out[(size_t)seg * 3 + 1] = sy * inv;
        out[(size_t)seg * 3 + 2] = sz * inv;
    }
}

// ---- zero padding rows >= n_vox ----
__global__ void pad_kernel(float* __restrict__ out,
                           const uint32_t* __restrict__ totals, int N, int C) {
    uint32_t nvox = totals[0];
    size_t gid = (size_t)blockIdx.x * blockDim.x + threadIdx.x;
    size_t stride = (size_t)gridDim.x * blockDim.x;
    float* featBase = out + (size_t)N * 3;
    f32x4 z4 = {0.f, 0.f, 0.f, 0.f};
    if ((C & 3) == 0) {
        f32x4* f4 = (f32x4*)featBase;
        size_t r4 = (size_t)C / 4;
        size_t v0 = (size_t)nvox * r4, v1 = (size_t)N * r4;
        for (size_t v = v0 + gid; v < v1; v += stride)
            __builtin_nontemporal_store(z4, &f4[v]);
    } else {
        size_t e0 = (size_t)nvox * C, e1 = (size_t)N * C;
        for (size_t e = e0 + gid; e < e1; e += stride)
            __builtin_nontemporal_store(0.f, &featBase[e]);
    }
    size_t c0 = (size_t)nvox * 3, c1 = (size_t)N * 3;
    for (size_t e = c0 + gid; e < c1; e += stride)
        __builtin_nontemporal_store(0.f, &out[e]);
}

// ---- offset_out + n_vox ----
__global__ void finalize_kernel(const uint32_t* __restrict__ binSeg,
                                const uint32_t* __restrict__ totals,
                                float* __restrict__ out, int B, int N, int C) {
    int t = threadIdx.x;
    uint32_t nvox = totals[0];
    float* tail = out + (size_t)N * 3 + (size_t)N * C;
    if (t < B) {
        uint32_t v = (t == B - 1) ? nvox
                                  : binSeg[(size_t)(t + 1) * BINS_PER_BATCH];
        tail[t] = (float)v;
    }
    if (t == 0) tail[B] = (float)nvox;
}

extern "C" void kernel_launch(void* const* d_in, const int* in_sizes, int n_in,
                              void* d_out, int out_size, void* d_ws, size_t ws_size,
                              hipStream_t stream) {
    const float* coord = (const float*)d_in[0];
    const float* feat  = (const float*)d_in[1];
    const int*   offs  = (const int*)d_in[2];
    float* out = (float*)d_out;

    int N = in_sizes[0] / 3;
    int C = in_sizes[1] / N;
    int B = in_sizes[2];
    int NBINS = B * BINS_PER_BATCH;          // 131072 for B=4
    int NB1 = NBINS / BINS_PER_BLOCK;        // 128

    // workspace layout
    uint8_t* w = (uint8_t*)d_ws;
    uint32_t* binCount = (uint32_t*)w;              w += (size_t)NBINS * 4;
    uint32_t* binStart = (uint32_t*)w;              w += (size_t)NBINS * 4;
    uint32_t* binSeg   = (uint32_t*)w;              w += (size_t)NBINS * 4;
    uint32_t* blockCnt = (uint32_t*)w;              w += (size_t)NB1 * 4;
    uint32_t* blockOcc = (uint32_t*)w;              w += (size_t)NB1 * 4;
    uint32_t* totals   = (uint32_t*)w;              w += 2 * 4;
    int*      startBits= (int*)w;                   w += (size_t)3 * B * 4 + 8;
    uint32_t* keys     = (uint32_t*)w;              w += (size_t)N * 4;
    uint32_t* rank     = (uint32_t*)w;              w += (size_t)N * 4;
    uint32_t* pointIdx = (uint32_t*)w;              /* w += N*4 */

    int ptBlocks = (N + 255) / 256;

    init_kernel<<<512, 256, 0, stream>>>(binCount, NBINS, startBits, B);
    if (B <= 4) {
        batch_min4_kernel<<<1024, 256, 0, stream>>>(coord, offs, B, N, startBits);
    } else {
        batch_min_generic_kernel<<<ptBlocks, 256, 0, stream>>>(coord, offs, B, N,
                                                               startBits);
    }
    keys_count_kernel<<<ptBlocks, 256, 0, stream>>>(coord, offs, startBits, B, N,
                                                    keys, rank, binCount);
    scan1_kernel<<<NB1, SCAN_TPB, 0, stream>>>(binCount, binStart, binSeg,
                                               blockCnt, blockOcc);
    scan2_kernel<<<1, SCAN_TPB, 0, stream>>>(blockCnt, blockOcc, totals, NB1);
    scan3_kernel<<<NB1, SCAN_TPB, 0, stream>>>(binStart, binSeg, blockCnt, blockOcc);
    scatter_kernel<<<ptBlocks, 256, 0, stream>>>(keys, rank, binStart, pointIdx, N);
    reduce_kernel<<<NBINS, 64, 0, stream>>>(coord, feat, binCount, binStart,
                                            binSeg, pointIdx, out, N, C);
    pad_kernel<<<2048, 256, 0, stream>>>(out, totals, N, C);
    finalize_kernel<<<1, 64, 0, stream>>>(binSeg, totals, out, B, N, C);
}

// Round 6
// 207.107 us; speedup vs baseline: 2.1836x; 1.1136x over previous
//
#include <hip/hip_runtime.h>
#include <hip/hip_bf16.h>
#include <cstdint>

#define AXIS_CAP 32
#define GRID_SIZE_F 0.04f
#define BINS_PER_BATCH (AXIS_CAP * AXIS_CAP * AXIS_CAP)   // 32768
#define SCAN_TPB 256
#define BINS_PER_THREAD 4
#define BINS_PER_BLOCK (SCAN_TPB * BINS_PER_THREAD)       // 1024
#define KC_PPT 4                                           // keys_count pts/thread

typedef float f32x4 __attribute__((ext_vector_type(4)));  // nontemporal-legal

__device__ __forceinline__ int point_batch(int i, const int* offs, int B) {
    int b = 0;
    for (int k = 0; k < B; ++k) b += (offs[k] <= i);
    return b;
}

// ---- init scratch ----
__global__ void init_kernel(uint32_t* binCount, int nbins, int* startBits, int B) {
    int i = blockIdx.x * blockDim.x + threadIdx.x;
    int stride = gridDim.x * blockDim.x;
    for (int v = i; v < nbins; v += stride) binCount[v] = 0;
    if (i < 3 * B) startBits[i] = 0x7F800000;  // +inf
}

// ---- per-batch min coord, hierarchical: reg -> wave shuffle -> LDS -> global ----
__global__ __launch_bounds__(256) void batch_min4_kernel(
        const float* __restrict__ coord, const int* __restrict__ offs,
        int B, int N, int* __restrict__ startBits) {
    __shared__ int smin[12];
    if (threadIdx.x < 12) smin[threadIdx.x] = 0x7F800000;
    __syncthreads();

    int o0 = offs[0];
    int o1 = (B > 1) ? offs[1] : o0;
    int o2 = (B > 2) ? offs[2] : o1;

    float m[4][3];
#pragma unroll
    for (int bb = 0; bb < 4; ++bb)
#pragma unroll
        for (int d = 0; d < 3; ++d) m[bb][d] = INFINITY;

    int gid = blockIdx.x * blockDim.x + threadIdx.x;
    int stride = gridDim.x * blockDim.x;
    for (int i = gid; i < N; i += stride) {
        float x = coord[(size_t)i * 3 + 0];
        float y = coord[(size_t)i * 3 + 1];
        float z = coord[(size_t)i * 3 + 2];
        int b = (i >= o0) + (i >= o1) + (i >= o2);
#pragma unroll
        for (int bb = 0; bb < 4; ++bb) {
            bool sel = (bb == b);
            m[bb][0] = fminf(m[bb][0], sel ? x : INFINITY);
            m[bb][1] = fminf(m[bb][1], sel ? y : INFINITY);
            m[bb][2] = fminf(m[bb][2], sel ? z : INFINITY);
        }
    }

#pragma unroll
    for (int bb = 0; bb < 4; ++bb)
#pragma unroll
        for (int d = 0; d < 3; ++d) {
            float v = m[bb][d];
            for (int off = 32; off > 0; off >>= 1)
                v = fminf(v, __shfl_xor(v, off));
            m[bb][d] = v;
        }

    if ((threadIdx.x & 63) == 0) {
#pragma unroll
        for (int bb = 0; bb < 4; ++bb)
#pragma unroll
            for (int d = 0; d < 3; ++d)
                atomicMin(&smin[bb * 3 + d], __float_as_int(m[bb][d]));
    }
    __syncthreads();
    if (threadIdx.x < 12 && (threadIdx.x / 3) < B)
        atomicMin(&startBits[threadIdx.x], smin[threadIdx.x]);
}

// ---- generic fallback for B > 4 ----
__global__ void batch_min_generic_kernel(const float* __restrict__ coord,
                                         const int* __restrict__ offs,
                                         int B, int N, int* startBits) {
    int i = blockIdx.x * blockDim.x + threadIdx.x;
    if (i >= N) return;
    int b = point_batch(i, offs, B);
    for (int d = 0; d < 3; ++d) {
        float c = coord[(size_t)i * 3 + d];
        atomicMin(&startBits[b * 3 + d], __float_as_int(c));
    }
}

// ---- per-point voxel key + histogram (B<=4 fast path) ----
// KC_PPT points per thread -> KC_PPT independent atomics in flight.
// atomicAdd's return value is the in-bin rank; (key,rank) packed as uint2.
__global__ __launch_bounds__(256) void keys_count4_kernel(
        const float* __restrict__ coord, const int* __restrict__ offs,
        const int* __restrict__ startBits, int B, int N,
        uint2* __restrict__ kr, uint32_t* __restrict__ binCount) {
    int o0 = offs[0];
    int o1 = (B > 1) ? offs[1] : o0;
    int o2 = (B > 2) ? offs[2] : o1;
    // hoist the 12 start values into registers (compile-time indexed)
    float s00 = __int_as_float(startBits[0]);
    float s01 = __int_as_float(startBits[1]);
    float s02 = __int_as_float(startBits[2]);
    float s10 = (B > 1) ? __int_as_float(startBits[3]) : 0.f;
    float s11 = (B > 1) ? __int_as_float(startBits[4]) : 0.f;
    float s12 = (B > 1) ? __int_as_float(startBits[5]) : 0.f;
    float s20 = (B > 2) ? __int_as_float(startBits[6]) : 0.f;
    float s21 = (B > 2) ? __int_as_float(startBits[7]) : 0.f;
    float s22 = (B > 2) ? __int_as_float(startBits[8]) : 0.f;
    float s30 = (B > 3) ? __int_as_float(startBits[9]) : 0.f;
    float s31 = (B > 3) ? __int_as_float(startBits[10]) : 0.f;
    float s32 = (B > 3) ? __int_as_float(startBits[11]) : 0.f;

    int i0 = blockIdx.x * (256 * KC_PPT) + threadIdx.x;
#pragma unroll
    for (int j = 0; j < KC_PPT; ++j) {
        int i = i0 + j * 256;
        if (i >= N) continue;
        float x = coord[(size_t)i * 3 + 0];
        float y = coord[(size_t)i * 3 + 1];
        float z = coord[(size_t)i * 3 + 2];
        int b = (i >= o0) + (i >= o1) + (i >= o2);
        float sx = (b == 0) ? s00 : (b == 1) ? s10 : (b == 2) ? s20 : s30;
        float sy = (b == 0) ? s01 : (b == 1) ? s11 : (b == 2) ? s21 : s31;
        float sz = (b == 0) ? s02 : (b == 1) ? s12 : (b == 2) ? s22 : s32;
        int vx = (int)floorf((x - sx) / GRID_SIZE_F);
        int vy = (int)floorf((y - sy) / GRID_SIZE_F);
        int vz = (int)floorf((z - sz) / GRID_SIZE_F);
        vx = vx < 0 ? 0 : (vx > AXIS_CAP - 1 ? AXIS_CAP - 1 : vx);
        vy = vy < 0 ? 0 : (vy > AXIS_CAP - 1 ? AXIS_CAP - 1 : vy);
        vz = vz < 0 ? 0 : (vz > AXIS_CAP - 1 ? AXIS_CAP - 1 : vz);
        uint32_t key = ((uint32_t)b * AXIS_CAP + vx) * AXIS_CAP * AXIS_CAP
                     + (uint32_t)vy * AXIS_CAP + vz;
        uint32_t r = atomicAdd(&binCount[key], 1u);
        kr[i] = make_uint2(key, r);
    }
}

// ---- generic keys_count for B > 4 ----
__global__ void keys_count_generic_kernel(
        const float* __restrict__ coord, const int* __restrict__ offs,
        const int* __restrict__ startBits, int B, int N,
        uint2* __restrict__ kr, uint32_t* __restrict__ binCount) {
    int i = blockIdx.x * blockDim.x + threadIdx.x;
    if (i >= N) return;
    int b = point_batch(i, offs, B);
    int v[3];
    for (int d = 0; d < 3; ++d) {
        float s = __int_as_float(startBits[b * 3 + d]);
        float q = (coord[(size_t)i * 3 + d] - s) / GRID_SIZE_F;
        int vi = (int)floorf(q);
        vi = vi < 0 ? 0 : (vi > AXIS_CAP - 1 ? AXIS_CAP - 1 : vi);
        v[d] = vi;
    }
    uint32_t key = ((uint32_t)b * AXIS_CAP + v[0]) * AXIS_CAP * AXIS_CAP
                 + (uint32_t)v[1] * AXIS_CAP + v[2];
    uint32_t r = atomicAdd(&binCount[key], 1u);
    kr[i] = make_uint2(key, r);
}

// ---- scan pass 1 ----
__global__ void scan1_kernel(const uint32_t* __restrict__ binCount,
                             uint32_t* __restrict__ binStart,
                             uint32_t* __restrict__ binSeg,
                             uint32_t* __restrict__ blockCnt,
                             uint32_t* __restrict__ blockOcc) {
    __shared__ uint32_t sC[SCAN_TPB], sO[SCAN_TPB];
    int t = threadIdx.x;
    int base = blockIdx.x * BINS_PER_BLOCK + t * BINS_PER_THREAD;
    uint32_t c[BINS_PER_THREAD];
    uint32_t tc = 0, to = 0;
#pragma unroll
    for (int j = 0; j < BINS_PER_THREAD; ++j) {
        c[j] = binCount[base + j];
        tc += c[j];
        to += (c[j] > 0u);
    }
    sC[t] = tc; sO[t] = to;
    __syncthreads();
    for (int off = 1; off < SCAN_TPB; off <<= 1) {
        uint32_t a = 0, b2 = 0;
        if (t >= off) { a = sC[t - off]; b2 = sO[t - off]; }
        __syncthreads();
        sC[t] += a; sO[t] += b2;
        __syncthreads();
    }
    uint32_t exC = sC[t] - tc;
    uint32_t exO = sO[t] - to;
#pragma unroll
    for (int j = 0; j < BINS_PER_THREAD; ++j) {
        binStart[base + j] = exC;
        binSeg[base + j] = exO;
        exC += c[j];
        exO += (c[j] > 0u);
    }
    if (t == SCAN_TPB - 1) {
        blockCnt[blockIdx.x] = sC[t];
        blockOcc[blockIdx.x] = sO[t];
    }
}

// ---- scan pass 2 ----
__global__ void scan2_kernel(uint32_t* blockCnt, uint32_t* blockOcc,
                             uint32_t* totals, int nb) {
    __shared__ uint32_t sC[SCAN_TPB], sO[SCAN_TPB];
    int t = threadIdx.x;
    uint32_t c = (t < nb) ? blockCnt[t] : 0u;
    uint32_t o = (t < nb) ? blockOcc[t] : 0u;
    sC[t] = c; sO[t] = o;
    __syncthreads();
    for (int off = 1; off < SCAN_TPB; off <<= 1) {
        uint32_t a = 0, b2 = 0;
        if (t >= off) { a = sC[t - off]; b2 = sO[t - off]; }
        __syncthreads();
        sC[t] += a; sO[t] += b2;
        __syncthreads();
    }
    if (t < nb) { blockCnt[t] = sC[t] - c; blockOcc[t] = sO[t] - o; }
    if (t == SCAN_TPB - 1) { totals[0] = sO[t]; totals[1] = sC[t]; }
}

// ---- scan pass 3: add block offsets ----
__global__ void scan3_kernel(uint32_t* __restrict__ binStart,
                             uint32_t* __restrict__ binSeg,
                             const uint32_t* __restrict__ blockCnt,
                             const uint32_t* __restrict__ blockOcc) {
    int t = threadIdx.x;
    int base = blockIdx.x * BINS_PER_BLOCK + t * BINS_PER_THREAD;
    uint32_t oc = blockCnt[blockIdx.x];
    uint32_t oo = blockOcc[blockIdx.x];
#pragma unroll
    for (int j = 0; j < BINS_PER_THREAD; ++j) {
        binStart[base + j] += oc;
        binSeg[base + j] += oo;
    }
}

// ---- scatter: atomic-free (pos = binStart[key] + rank); block 0 also
// writes the offset_out/n_vox tail ----
__global__ void scatter_kernel(const uint2* __restrict__ kr,
                               const uint32_t* __restrict__ binStart,
                               uint32_t* __restrict__ pointIdx, int N,
                               const uint32_t* __restrict__ binSeg,
                               const uint32_t* __restrict__ totals,
                               float* __restrict__ out, int B, int C) {
    int i = blockIdx.x * blockDim.x + threadIdx.x;
    if (blockIdx.x == 0 && threadIdx.x <= (unsigned)B) {
        uint32_t nvox = totals[0];
        float* tail = out + (size_t)N * 3 + (size_t)N * C;
        if (threadIdx.x < (unsigned)B) {
            uint32_t v = (threadIdx.x == (unsigned)(B - 1))
                             ? nvox
                             : binSeg[(size_t)(threadIdx.x + 1) * BINS_PER_BATCH];
            tail[threadIdx.x] = (float)v;
        }
        if (threadIdx.x == 0) tail[B] = (float)nvox;
    }
    if (i >= N) return;
    uint2 k = kr[i];
    pointIdx[binStart[k.x] + k.y] = (uint32_t)i;
}

// ---- per-voxel reduction + distributed zero-padding ----
// One 64-thread wave per bin. Occupied bins: feat max (4 row-groups x 16
// lanes, float4/lane) + coord mean. ALL blocks additionally zero an equal
// chunk of the padded region (rows >= n_vox), overlapping pad writes with
// gather latency.
__global__ __launch_bounds__(64) void reduce_kernel(
        const float* __restrict__ coord, const float* __restrict__ feat,
        const uint32_t* __restrict__ binCount,
        const uint32_t* __restrict__ binStart,
        const uint32_t* __restrict__ binSeg,
        const uint32_t* __restrict__ pointIdx,
        const uint32_t* __restrict__ totals,
        float* __restrict__ out, int N, int C) {
    int bin = blockIdx.x;
    uint32_t cnt = binCount[bin];
    int lane = threadIdx.x;
    float* feat_out = out + (size_t)N * 3;

    if (cnt != 0u) {
        uint32_t st = binStart[bin];
        uint32_t seg = binSeg[bin];
        float sx = 0.f, sy = 0.f, sz = 0.f;

        if ((C & 3) == 0 && C <= 64) {
            int g = lane >> 4;          // row group 0..3
            int l4 = lane & 15;         // float4 slot within row
            int q4 = C >> 2;            // float4s per row
            f32x4 mx = {-INFINITY, -INFINITY, -INFINITY, -INFINITY};
            for (uint32_t base = 0; base < cnt; base += 64) {
                uint32_t nchunk = min(64u, cnt - base);
                bool valid = lane < (int)nchunk;
                uint32_t myIdx = valid ? pointIdx[st + base + lane] : 0u;
                if (valid) {
                    sx += coord[(size_t)myIdx * 3 + 0];
                    sy += coord[(size_t)myIdx * 3 + 1];
                    sz += coord[(size_t)myIdx * 3 + 2];
                }
                for (uint32_t p = (uint32_t)g; p < nchunk; p += 4) {
                    uint32_t idx = __shfl(myIdx, (int)p);
                    if (l4 < q4) {
                        const f32x4* row = (const f32x4*)(feat + (size_t)idx * C);
                        f32x4 v = row[l4];
                        mx.x = fmaxf(mx.x, v.x);
                        mx.y = fmaxf(mx.y, v.y);
                        mx.z = fmaxf(mx.z, v.z);
                        mx.w = fmaxf(mx.w, v.w);
                    }
                }
            }
            mx.x = fmaxf(mx.x, __shfl_xor(mx.x, 16));
            mx.y = fmaxf(mx.y, __shfl_xor(mx.y, 16));
            mx.z = fmaxf(mx.z, __shfl_xor(mx.z, 16));
            mx.w = fmaxf(mx.w, __shfl_xor(mx.w, 16));
            mx.x = fmaxf(mx.x, __shfl_xor(mx.x, 32));
            mx.y = fmaxf(mx.y, __shfl_xor(mx.y, 32));
            mx.z = fmaxf(mx.z, __shfl_xor(mx.z, 32));
            mx.w = fmaxf(mx.w, __shfl_xor(mx.w, 32));
            if (g == 0 && l4 < q4)
                ((f32x4*)(feat_out + (size_t)seg * C))[l4] = mx;
        } else {
            for (uint32_t p = lane; p < cnt; p += 64) {
                uint32_t idx = pointIdx[st + p];
                sx += coord[(size_t)idx * 3 + 0];
                sy += coord[(size_t)idx * 3 + 1];
                sz += coord[(size_t)idx * 3 + 2];
            }
            for (int c = lane; c < C; c += 64) {
                float m = -INFINITY;
                for (uint32_t p = 0; p < cnt; ++p) {
                    uint32_t idx = pointIdx[st + p];
                    m = fmaxf(m, feat[(size_t)idx * C + c]);
                }
                feat_out[(size_t)seg * C + c] = m;
            }
        }

        for (int off = 32; off > 0; off >>= 1) {
            sx += __shfl_xor(sx, off);
            sy += __shfl_xor(sy, off);
            sz += __shfl_xor(sz, off);
        }
        if (lane == 0) {
            float inv = 1.0f / (float)cnt;
            out[(size_t)seg * 3 + 0] = sx * inv;
            out[(size_t)seg * 3 + 1] = sy * inv;
            out[(size_t)seg * 3 + 2] = sz * inv;
        }
    }

    // distributed zero-pad of rows >= n_vox (every block takes a chunk)
    uint32_t nvox = totals[0];
    uint32_t nb = gridDim.x;
    if ((C & 3) == 0) {
        f32x4 z4 = {0.f, 0.f, 0.f, 0.f};
        size_t q4r = (size_t)(C >> 2);
        size_t quadsTotal = (size_t)(N - (int)nvox) * q4r;
        size_t chunk = (quadsTotal + nb - 1) / nb;
        size_t q0 = (size_t)bin * chunk;
        size_t q1 = min(q0 + chunk, quadsTotal);
        f32x4* padBase = (f32x4*)(feat_out + (size_t)nvox * C);
        for (size_t q = q0 + lane; q < q1; q += 64)
            __builtin_nontemporal_store(z4, &padBase[q]);
    } else {
        size_t eTotal = (size_t)(N - (int)nvox) * C;
        size_t chunk = (eTotal + nb - 1) / nb;
        size_t e0 = (size_t)bin * chunk;
        size_t e1 = min(e0 + chunk, eTotal);
        float* padBase = feat_out + (size_t)nvox * C;
        for (size_t e = e0 + lane; e < e1; e += 64)
            __builtin_nontemporal_store(0.f, &padBase[e]);
    }
    {
        size_t cTotal = (size_t)(N - (int)nvox) * 3;
        size_t chunk = (cTotal + nb - 1) / nb;
        size_t e0 = (size_t)bin * chunk;
        size_t e1 = min(e0 + chunk, cTotal);
        float* cBase = out + (size_t)nvox * 3;
        for (size_t e = e0 + lane; e < e1; e += 64)
            __builtin_nontemporal_store(0.f, &cBase[e]);
    }
}

extern "C" void kernel_launch(void* const* d_in, const int* in_sizes, int n_in,
                              void* d_out, int out_size, void* d_ws, size_t ws_size,
                              hipStream_t stream) {
    const float* coord = (const float*)d_in[0];
    const float* feat  = (const float*)d_in[1];
    const int*   offs  = (const int*)d_in[2];
    float* out = (float*)d_out;

    int N = in_sizes[0] / 3;
    int C = in_sizes[1] / N;
    int B = in_sizes[2];
    int NBINS = B * BINS_PER_BATCH;          // 131072 for B=4
    int NB1 = NBINS / BINS_PER_BLOCK;        // 128

    // workspace layout
    uint8_t* w = (uint8_t*)d_ws;
    uint32_t* binCount = (uint32_t*)w;              w += (size_t)NBINS * 4;
    uint32_t* binStart = (uint32_t*)w;              w += (size_t)NBINS * 4;
    uint32_t* binSeg   = (uint32_t*)w;              w += (size_t)NBINS * 4;
    uint32_t* blockCnt = (uint32_t*)w;              w += (size_t)NB1 * 4;
    uint32_t* blockOcc = (uint32_t*)w;              w += (size_t)NB1 * 4;
    uint32_t* totals   = (uint32_t*)w;              w += 2 * 4;
    int*      startBits= (int*)w;                   w += (size_t)3 * B * 4 + 8;
    uint2*    kr       = (uint2*)w;                 w += (size_t)N * 8;
    uint32_t* pointIdx = (uint32_t*)w;              /* w += N*4 */

    int ptBlocks = (N + 255) / 256;
    int kcBlocks = (N + 256 * KC_PPT - 1) / (256 * KC_PPT);

    init_kernel<<<512, 256, 0, stream>>>(binCount, NBINS, startBits, B);
    if (B <= 4) {
        batch_min4_kernel<<<1024, 256, 0, stream>>>(coord, offs, B, N, startBits);
        keys_count4_kernel<<<kcBlocks, 256, 0, stream>>>(coord, offs, startBits,
                                                         B, N, kr, binCount);
    } else {
        batch_min_generic_kernel<<<ptBlocks, 256, 0, stream>>>(coord, offs, B, N,
                                                               startBits);
        keys_count_generic_kernel<<<ptBlocks, 256, 0, stream>>>(coord, offs,
                                                                startBits, B, N,
                                                                kr, binCount);
    }
    scan1_kernel<<<NB1, SCAN_TPB, 0, stream>>>(binCount, binStart, binSeg,
                                               blockCnt, blockOcc);
    scan2_kernel<<<1, SCAN_TPB, 0, stream>>>(blockCnt, blockOcc, totals, NB1);
    scan3_kernel<<<NB1, SCAN_TPB, 0, stream>>>(binStart, binSeg, blockCnt, blockOcc);
    scatter_kernel<<<ptBlocks, 256, 0, stream>>>(kr, binStart, pointIdx, N,
                                                 binSeg, totals, out, B, C);
    reduce_kernel<<<NBINS, 64, 0, stream>>>(coord, feat, binCount, binStart,
                                            binSeg, pointIdx, totals, out, N, C);
}